// Round 1
// baseline (162.339 us; speedup 1.0000x reference)
//
#include <hip/hip_runtime.h>

#define EPS 1e-5f

// Broadcast a block-uniform load into an SGPR (weights, scalars).
__device__ __forceinline__ float uload(const float* __restrict__ p) {
  return __int_as_float(__builtin_amdgcn_readfirstlane(__float_as_int(*p)));
}

// ---------------------------------------------------------------------------
// K1: conv1 (1->8ch, 3x3, SAME) + ReLU + 2x2 maxpool.
// x: (512,1,128,128) -> pooled1: (512,8,64,64)
// Block = 256 threads handles (b, 4 pooled rows) for ALL 8 output channels;
// x tile (10 rows x 130 cols, zero-padded) staged once in LDS.
// ---------------------------------------------------------------------------
__global__ __launch_bounds__(256) void k1_conv_pool(
    const float* __restrict__ x, const float* __restrict__ w1,
    const float* __restrict__ b1, float* __restrict__ pooled1) {
  __shared__ float tile[10][132];
  const int bi  = blockIdx.x;
  const int ych = bi & 15;        // 16 chunks of 4 pooled rows
  const int b   = bi >> 4;        // 0..511
  const int tid = threadIdx.x;
  const int iy0 = ych * 8 - 1;    // first x row needed (2*py0 - 1)
  const float* xb = x + (size_t)b * (128 * 128);

  for (int idx = tid; idx < 10 * 132; idx += 256) {
    int r = idx / 132, c = idx - r * 132;
    int gy = iy0 + r, gc = c - 1;
    float v = 0.f;
    if (gy >= 0 && gy < 128 && gc >= 0 && gc < 128) v = xb[gy * 128 + gc];
    tile[r][c] = v;
  }
  __syncthreads();

  const int px  = tid & 63;
  const int pyl = tid >> 6;       // 0..3
  const int py  = ych * 4 + pyl;

  float xin[4][4];
#pragma unroll
  for (int r = 0; r < 4; ++r)
#pragma unroll
    for (int c = 0; c < 4; ++c)
      xin[r][c] = tile[2 * pyl + r][2 * px + c];  // stride-2 lanes: 2-way, free

  float* outb = pooled1 + (size_t)b * 8 * 4096 + py * 64 + px;
#pragma unroll 1
  for (int oc = 0; oc < 8; ++oc) {
    float wv[9];
#pragma unroll
    for (int k = 0; k < 9; ++k) wv[k] = uload(w1 + oc * 9 + k);
    float bias = uload(b1 + oc);
    float best = 0.f;  // relu clamps at 0, so max(relu(.)) starts at 0
#pragma unroll
    for (int dy = 0; dy < 2; ++dy)
#pragma unroll
      for (int dx = 0; dx < 2; ++dx) {
        float a = bias;
#pragma unroll
        for (int ky = 0; ky < 3; ++ky)
#pragma unroll
          for (int kx = 0; kx < 3; ++kx)
            a = fmaf(xin[dy + ky][dx + kx], wv[ky * 3 + kx], a);
        best = fmaxf(best, a);
      }
    outb[oc * 4096] = best;  // coalesced: px contiguous across lanes
  }
}

// ---------------------------------------------------------------------------
// K2: conv2 (8->4ch used of 16, 3x3, SAME) + ReLU + 2x2 maxpool + spatial sum.
// pooled1: (512,8,64,64) -> partials: (512, 4 strips, 4 oc)
// Block = 256 threads handles (b, strip of 8 pooled2 rows), all 4 needed oc.
// pooled1 tile (8ch x 18 rows x 66 cols, zero-padded) staged in LDS (38 KB).
// ---------------------------------------------------------------------------
__global__ __launch_bounds__(256) void k2_conv_pool_mean(
    const float* __restrict__ pooled1, const float* __restrict__ w2,
    const float* __restrict__ b2, float* __restrict__ partials) {
  __shared__ float tile[8][18][66];
  __shared__ float wred[4][4];
  const int strip = blockIdx.x & 3;
  const int b     = blockIdx.x >> 2;
  const int tid   = threadIdx.x;
  const int gy0   = strip * 16 - 1;  // first pooled1 row needed
  const float* pb = pooled1 + (size_t)b * 8 * 4096;

  for (int idx = tid; idx < 8 * 18 * 66; idx += 256) {
    int ic  = idx / (18 * 66);
    int rem = idx - ic * (18 * 66);
    int r = rem / 66, c = rem - r * 66;
    int gy = gy0 + r, gc = c - 1;
    float v = 0.f;
    if (gy >= 0 && gy < 64 && gc >= 0 && gc < 64) v = pb[ic * 4096 + gy * 64 + gc];
    tile[ic][r][c] = v;
  }
  __syncthreads();

  const int px  = tid & 31;
  const int pyl = tid >> 5;  // 0..7

  float acc[4][2][2];
#pragma unroll
  for (int oc = 0; oc < 4; ++oc) {
    float bias = uload(b2 + oc);
    acc[oc][0][0] = bias; acc[oc][0][1] = bias;
    acc[oc][1][0] = bias; acc[oc][1][1] = bias;
  }

#pragma unroll 1
  for (int ic = 0; ic < 8; ++ic) {
    float xin[4][4];
#pragma unroll
    for (int r = 0; r < 4; ++r)
#pragma unroll
      for (int c = 0; c < 4; ++c)
        xin[r][c] = tile[ic][2 * pyl + r][2 * px + c];
#pragma unroll
    for (int oc = 0; oc < 4; ++oc) {
      float wv[9];
#pragma unroll
      for (int k = 0; k < 9; ++k) wv[k] = uload(w2 + (oc * 8 + ic) * 9 + k);
#pragma unroll
      for (int dy = 0; dy < 2; ++dy)
#pragma unroll
        for (int dx = 0; dx < 2; ++dx) {
#pragma unroll
          for (int ky = 0; ky < 3; ++ky)
#pragma unroll
            for (int kx = 0; kx < 3; ++kx)
              acc[oc][dy][dx] =
                  fmaf(xin[dy + ky][dx + kx], wv[ky * 3 + kx], acc[oc][dy][dx]);
        }
    }
  }

  const int lane = tid & 63, w = tid >> 6;
#pragma unroll
  for (int oc = 0; oc < 4; ++oc) {
    float p = fmaxf(fmaxf(fmaxf(acc[oc][0][0], acc[oc][0][1]),
                          fmaxf(acc[oc][1][0], acc[oc][1][1])), 0.f);
#pragma unroll
    for (int off = 32; off > 0; off >>= 1) p += __shfl_down(p, off);
    if (lane == 0) wred[w][oc] = p;
  }
  __syncthreads();
  if (tid < 4) {
    float s = wred[0][tid] + wred[1][tid] + wred[2][tid] + wred[3][tid];
    partials[((size_t)b * 4 + strip) * 4 + tid] = s;
  }
}

// ---------------------------------------------------------------------------
// K3: feats -> quantum circuit -> batchnorm (over batch=512) -> head.
// Single block, 512 threads; thread = batch element.
// ---------------------------------------------------------------------------
__global__ __launch_bounds__(512) void k3_tail(
    const float* __restrict__ partials, const float* __restrict__ qp,
    const float* __restrict__ gamma, const float* __restrict__ beta,
    const float* __restrict__ hw, const float* __restrict__ hb,
    float* __restrict__ out) {
  __shared__ float red[512];
  __shared__ float stats[8];
  const int tid = threadIdx.x;  // batch index

  float f[4];
#pragma unroll
  for (int i = 0; i < 4; ++i)
    f[i] = (partials[tid * 16 + i] + partials[tid * 16 + 4 + i] +
            partials[tid * 16 + 8 + i] + partials[tid * 16 + 12 + i]) *
           (1.f / 1024.f);

  // Per-wire single-qubit amplitudes: a0 = cx*cy - i*sx*sy, a1 = cx*sy - i*sx*cy
  float a0r[4], a0i[4], a1r[4], a1i[4];
#pragma unroll
  for (int i = 0; i < 4; ++i) {
    float hf = 0.5f * f[i];
    float hp = 0.5f * uload(qp + i);
    float cy = cosf(hf), sy = sinf(hf);
    float cx = cosf(hp), sx = sinf(hp);
    a0r[i] = cx * cy; a0i[i] = -sx * sy;
    a1r[i] = cx * sy; a1i[i] = -sx * cy;
  }

  // psi[j] = prod over wires of a_{bit}(wire), wire 0 = MSB
  float pr[16], pi[16];
#pragma unroll
  for (int j = 0; j < 16; ++j) {
    float rr = 1.f, ii = 0.f;
#pragma unroll
    for (int w = 0; w < 4; ++w) {
      int bit = (j >> (3 - w)) & 1;
      float ar = bit ? a1r[w] : a0r[w];
      float ai = bit ? a1i[w] : a0i[w];
      float t = rr * ar - ii * ai;
      ii = rr * ai + ii * ar;
      rr = t;
    }
    pr[j] = rr; pi[j] = ii;
  }

  // Composed CNOT(0,1);CNOT(1,2);CNOT(2,3) permutation (new[j] = old[comp[j]])
  constexpr int comp[16] = {0, 1, 3, 2, 6, 7, 5, 4, 12, 13, 15, 14, 10, 11, 9, 8};
  float q[4] = {0.f, 0.f, 0.f, 0.f};
#pragma unroll
  for (int j = 0; j < 16; ++j) {
    int s = comp[j];
    float p = pr[s] * pr[s] + pi[s] * pi[s];
#pragma unroll
    for (int i = 0; i < 4; ++i)
      q[i] += ((j >> (3 - i)) & 1) ? -p : p;
  }

  // Batch mean / mean-of-squares for each of 4 outputs
#pragma unroll 1
  for (int i = 0; i < 4; ++i) {
    red[tid] = q[i];
    __syncthreads();
    for (int s2 = 256; s2 > 0; s2 >>= 1) {
      if (tid < s2) red[tid] += red[tid + s2];
      __syncthreads();
    }
    if (tid == 0) stats[i] = red[0] * (1.f / 512.f);
    __syncthreads();
    red[tid] = q[i] * q[i];
    __syncthreads();
    for (int s2 = 256; s2 > 0; s2 >>= 1) {
      if (tid < s2) red[tid] += red[tid + s2];
      __syncthreads();
    }
    if (tid == 0) stats[4 + i] = red[0] * (1.f / 512.f);
    __syncthreads();
  }

  float nm[4];
#pragma unroll
  for (int i = 0; i < 4; ++i) {
    float mu  = stats[i];
    float var = stats[4 + i] - mu * mu;
    nm[i] = uload(gamma + i) * (q[i] - mu) * rsqrtf(var + EPS) + uload(beta + i);
  }
#pragma unroll
  for (int k = 0; k < 4; ++k) {
    float o = uload(hb + k);
#pragma unroll
    for (int i = 0; i < 4; ++i) o = fmaf(nm[i], uload(hw + k * 4 + i), o);
    out[tid * 4 + k] = o;
  }
}

extern "C" void kernel_launch(void* const* d_in, const int* in_sizes, int n_in,
                              void* d_out, int out_size, void* d_ws, size_t ws_size,
                              hipStream_t stream) {
  const float* x  = (const float*)d_in[0];
  const float* w1 = (const float*)d_in[1];
  const float* b1 = (const float*)d_in[2];
  const float* w2 = (const float*)d_in[3];
  const float* b2 = (const float*)d_in[4];
  const float* qp = (const float*)d_in[5];
  const float* gm = (const float*)d_in[6];
  const float* bt = (const float*)d_in[7];
  const float* hw = (const float*)d_in[8];
  const float* hb = (const float*)d_in[9];
  float* out = (float*)d_out;

  float* pooled1  = (float*)d_ws;                      // 512*8*64*64 floats = 64 MB
  float* partials = pooled1 + (size_t)512 * 8 * 4096;  // 512*16 floats

  k1_conv_pool<<<512 * 16, 256, 0, stream>>>(x, w1, b1, pooled1);
  k2_conv_pool_mean<<<512 * 4, 256, 0, stream>>>(pooled1, w2, b2, partials);
  k3_tail<<<1, 512, 0, stream>>>(partials, qp, gm, bt, hw, hb, out);
}

// Round 2
// 152.583 us; speedup vs baseline: 1.0639x; 1.0639x over previous
//
#include <hip/hip_runtime.h>

#define EPS 1e-5f

// Broadcast a block-uniform load into an SGPR (weights, scalars).
__device__ __forceinline__ float uload(const float* __restrict__ p) {
  return __int_as_float(__builtin_amdgcn_readfirstlane(__float_as_int(*p)));
}

// ---------------------------------------------------------------------------
// K12: fully fused conv1(1->8)+ReLU+pool + conv2(4 used oc of 16)+ReLU+pool
//      + spatial partial-sum. pooled1 lives only in LDS (no 64MB HBM trip).
// Block = (batch b, quarter q): pooled2 rows 8q..8q+7 (32 cols), 256 threads.
// LDS: xtile 38x132 fp32 (20.1KB) + p1tile 8x18x66 fp32 (38.0KB) = 58.1KB
//      -> 2 blocks/CU.
// ---------------------------------------------------------------------------
__global__ __launch_bounds__(256) void k12_fused(
    const float* __restrict__ x, const float* __restrict__ w1,
    const float* __restrict__ b1, const float* __restrict__ w2,
    const float* __restrict__ b2, float* __restrict__ partials) {
  __shared__ float xtile[38][132];
  __shared__ float p1[8][18][66];
  __shared__ float wred[4][4];

  const int q   = blockIdx.x & 3;
  const int b   = blockIdx.x >> 2;
  const int tid = threadIdx.x;
  const float* xb = x + (size_t)b * (128 * 128);

  // Hoist conv1 weights to SGPRs (block-uniform) — overlaps with staging.
  float wv1[8][9], bb1[8];
#pragma unroll
  for (int oc = 0; oc < 8; ++oc) {
#pragma unroll
    for (int k = 0; k < 9; ++k) wv1[oc][k] = uload(w1 + oc * 9 + k);
    bb1[oc] = uload(b1 + oc);
  }

  // ---- Stage x rows 32q-3 .. 32q+34 (zero-padded) ----
  const int xr0 = 32 * q - 3;
  for (int idx = tid; idx < 38 * 132; idx += 256) {
    int r = idx / 132, c = idx - r * 132;
    int gy = xr0 + r, gc = c - 1;
    float v = 0.f;
    if (gy >= 0 && gy < 128 && gc >= 0 && gc < 128) v = xb[gy * 128 + gc];
    xtile[r][c] = v;
  }
  __syncthreads();

  // ---- conv1 + ReLU + 2x2 pool -> p1[oc][gl][px+1], gl = 0..17 ----
  // pooled1 global row G = 16q - 1 + gl uses xtile rows 2gl..2gl+3.
#pragma unroll 1
  for (int pos = tid; pos < 18 * 64; pos += 256) {
    int gl = pos >> 6, px = pos & 63;
    int G = 16 * q - 1 + gl;
    bool valid = (G >= 0) && (G < 64);
    float xin[4][4];
#pragma unroll
    for (int r = 0; r < 4; ++r)
#pragma unroll
      for (int c = 0; c < 4; ++c)
        xin[r][c] = xtile[2 * gl + r][2 * px + c];
#pragma unroll
    for (int oc = 0; oc < 8; ++oc) {
      float best = 0.f;  // ReLU floor
#pragma unroll
      for (int dy = 0; dy < 2; ++dy)
#pragma unroll
        for (int dx = 0; dx < 2; ++dx) {
          float a = bb1[oc];
#pragma unroll
          for (int ky = 0; ky < 3; ++ky)
#pragma unroll
            for (int kx = 0; kx < 3; ++kx)
              a = fmaf(xin[dy + ky][dx + kx], wv1[oc][ky * 3 + kx], a);
          best = fmaxf(best, a);
        }
      p1[oc][gl][px + 1] = valid ? best : 0.f;
    }
  }
  // Zero the left/right halo columns (conv2 SAME padding).
  if (tid < 144) {
    int ic = tid / 18, gl = tid - ic * 18;
    p1[ic][gl][0] = 0.f;
    p1[ic][gl][65] = 0.f;
  }
  __syncthreads();

  // ---- conv2 (oc 0..3) + ReLU + 2x2 pool + accumulate ----
  const int px2  = tid & 31;
  const int py2l = tid >> 5;  // 0..7

  float acc[4][2][2];
#pragma unroll
  for (int oc = 0; oc < 4; ++oc) {
    float bias = uload(b2 + oc);
    acc[oc][0][0] = bias; acc[oc][0][1] = bias;
    acc[oc][1][0] = bias; acc[oc][1][1] = bias;
  }

#pragma unroll 1
  for (int ic = 0; ic < 8; ++ic) {
    float xin[4][4];
#pragma unroll
    for (int r = 0; r < 4; ++r)
#pragma unroll
      for (int c = 0; c < 4; ++c)
        xin[r][c] = p1[ic][2 * py2l + r][2 * px2 + c];
#pragma unroll
    for (int oc = 0; oc < 4; ++oc) {
      float wv[9];
#pragma unroll
      for (int k = 0; k < 9; ++k) wv[k] = uload(w2 + (oc * 8 + ic) * 9 + k);
#pragma unroll
      for (int dy = 0; dy < 2; ++dy)
#pragma unroll
        for (int dx = 0; dx < 2; ++dx) {
#pragma unroll
          for (int ky = 0; ky < 3; ++ky)
#pragma unroll
            for (int kx = 0; kx < 3; ++kx)
              acc[oc][dy][dx] =
                  fmaf(xin[dy + ky][dx + kx], wv[ky * 3 + kx], acc[oc][dy][dx]);
        }
    }
  }

  const int lane = tid & 63, w = tid >> 6;
#pragma unroll
  for (int oc = 0; oc < 4; ++oc) {
    float p = fmaxf(fmaxf(fmaxf(acc[oc][0][0], acc[oc][0][1]),
                          fmaxf(acc[oc][1][0], acc[oc][1][1])), 0.f);
#pragma unroll
    for (int off = 32; off > 0; off >>= 1) p += __shfl_down(p, off);
    if (lane == 0) wred[w][oc] = p;
  }
  __syncthreads();
  if (tid < 4) {
    float s = wred[0][tid] + wred[1][tid] + wred[2][tid] + wred[3][tid];
    partials[((size_t)b * 4 + q) * 4 + tid] = s;
  }
}

// ---------------------------------------------------------------------------
// K3: feats -> quantum circuit -> batchnorm (over batch=512) -> head.
// Single block, 512 threads; thread = batch element. Shuffle reductions.
// ---------------------------------------------------------------------------
__global__ __launch_bounds__(512) void k3_tail(
    const float* __restrict__ partials, const float* __restrict__ qp,
    const float* __restrict__ gamma, const float* __restrict__ beta,
    const float* __restrict__ hw, const float* __restrict__ hb,
    float* __restrict__ out) {
  __shared__ float wsum[8][8];
  __shared__ float stats[8];
  const int tid = threadIdx.x;  // batch index

  float f[4];
#pragma unroll
  for (int i = 0; i < 4; ++i)
    f[i] = (partials[tid * 16 + i] + partials[tid * 16 + 4 + i] +
            partials[tid * 16 + 8 + i] + partials[tid * 16 + 12 + i]) *
           (1.f / 1024.f);

  // Per-wire single-qubit amplitudes: a0 = cx*cy - i*sx*sy, a1 = cx*sy - i*sx*cy
  float a0r[4], a0i[4], a1r[4], a1i[4];
#pragma unroll
  for (int i = 0; i < 4; ++i) {
    float hf = 0.5f * f[i];
    float hp = 0.5f * uload(qp + i);
    float cy = cosf(hf), sy = sinf(hf);
    float cx = cosf(hp), sx = sinf(hp);
    a0r[i] = cx * cy; a0i[i] = -sx * sy;
    a1r[i] = cx * sy; a1i[i] = -sx * cy;
  }

  // psi[j] = prod over wires of a_{bit}(wire), wire 0 = MSB
  float pr[16], pi[16];
#pragma unroll
  for (int j = 0; j < 16; ++j) {
    float rr = 1.f, ii = 0.f;
#pragma unroll
    for (int w = 0; w < 4; ++w) {
      int bit = (j >> (3 - w)) & 1;
      float ar = bit ? a1r[w] : a0r[w];
      float ai = bit ? a1i[w] : a0i[w];
      float t = rr * ar - ii * ai;
      ii = rr * ai + ii * ar;
      rr = t;
    }
    pr[j] = rr; pi[j] = ii;
  }

  // Composed CNOT(0,1);CNOT(1,2);CNOT(2,3) permutation (new[j] = old[comp[j]])
  constexpr int comp[16] = {0, 1, 3, 2, 6, 7, 5, 4, 12, 13, 15, 14, 10, 11, 9, 8};
  float qv[4] = {0.f, 0.f, 0.f, 0.f};
#pragma unroll
  for (int j = 0; j < 16; ++j) {
    int s = comp[j];
    float p = pr[s] * pr[s] + pi[s] * pi[s];
#pragma unroll
    for (int i = 0; i < 4; ++i)
      qv[i] += ((j >> (3 - i)) & 1) ? -p : p;
  }

  // Batch sums of q and q^2 via wave shuffles, then cross-wave LDS combine.
  float v[8];
#pragma unroll
  for (int i = 0; i < 4; ++i) { v[i] = qv[i]; v[4 + i] = qv[i] * qv[i]; }
#pragma unroll
  for (int k = 0; k < 8; ++k)
#pragma unroll
    for (int off = 32; off > 0; off >>= 1) v[k] += __shfl_down(v[k], off);
  const int lane = tid & 63, w = tid >> 6;
  if (lane == 0) {
#pragma unroll
    for (int k = 0; k < 8; ++k) wsum[w][k] = v[k];
  }
  __syncthreads();
  if (tid < 8) {
    float s = 0.f;
#pragma unroll
    for (int ww = 0; ww < 8; ++ww) s += wsum[ww][tid];
    stats[tid] = s * (1.f / 512.f);
  }
  __syncthreads();

  float nm[4];
#pragma unroll
  for (int i = 0; i < 4; ++i) {
    float mu  = stats[i];
    float var = stats[4 + i] - mu * mu;
    nm[i] = uload(gamma + i) * (qv[i] - mu) * rsqrtf(var + EPS) + uload(beta + i);
  }
#pragma unroll
  for (int k = 0; k < 4; ++k) {
    float o = uload(hb + k);
#pragma unroll
    for (int i = 0; i < 4; ++i) o = fmaf(nm[i], uload(hw + k * 4 + i), o);
    out[tid * 4 + k] = o;
  }
}

extern "C" void kernel_launch(void* const* d_in, const int* in_sizes, int n_in,
                              void* d_out, int out_size, void* d_ws, size_t ws_size,
                              hipStream_t stream) {
  const float* x  = (const float*)d_in[0];
  const float* w1 = (const float*)d_in[1];
  const float* b1 = (const float*)d_in[2];
  const float* w2 = (const float*)d_in[3];
  const float* b2 = (const float*)d_in[4];
  const float* qp = (const float*)d_in[5];
  const float* gm = (const float*)d_in[6];
  const float* bt = (const float*)d_in[7];
  const float* hw = (const float*)d_in[8];
  const float* hb = (const float*)d_in[9];
  float* out = (float*)d_out;

  float* partials = (float*)d_ws;  // 512 * 4 strips * 4 oc floats = 32 KB

  k12_fused<<<512 * 4, 256, 0, stream>>>(x, w1, b1, w2, b2, partials);
  k3_tail<<<1, 512, 0, stream>>>(partials, qp, gm, bt, hw, hb, out);
}

// Round 3
// 124.811 us; speedup vs baseline: 1.3007x; 1.2225x over previous
//
#include <hip/hip_runtime.h>

#define EPS 1e-5f

typedef float f2 __attribute__((ext_vector_type(2)));
typedef float f4 __attribute__((ext_vector_type(4)));

// Broadcast a block-uniform load into an SGPR (weights, scalars).
__device__ __forceinline__ float uload(const float* __restrict__ p) {
  return __int_as_float(__builtin_amdgcn_readfirstlane(__float_as_int(*p)));
}

// ---------------------------------------------------------------------------
// K12: fused conv1(1->8)+ReLU+pool + conv2(4 used oc of 16)+ReLU+pool + sum.
// Block = (batch b, quarter q): pooled2 rows 8q..8q+7, 256 threads.
// conv1 reads x DIRECTLY from global (L1-served, 2-4x lane overlap) — no
// xtile. LDS = p1 only: 8ch x 18 x 66 fp32 = 38.0KB -> 4 blocks/CU
// (16 waves/CU) vs round-2's 2 blocks/CU. That's the latency-hiding fix.
// ---------------------------------------------------------------------------
__global__ __launch_bounds__(256, 4) void k12_fused(
    const float* __restrict__ x, const float* __restrict__ w1,
    const float* __restrict__ b1, const float* __restrict__ w2,
    const float* __restrict__ b2, float* __restrict__ partials) {
  __shared__ float p1[8][18][66];
  __shared__ float wred[4][4];

  const int q   = blockIdx.x & 3;
  const int b   = blockIdx.x >> 2;
  const int tid = threadIdx.x;
  const float* xb = x + (size_t)b * (128 * 128);

  // Zero conv2's SAME-padding halo columns while weights load.
  if (tid < 144) {
    int ic = tid / 18, gl = tid - ic * 18;
    p1[ic][gl][0]  = 0.f;
    p1[ic][gl][65] = 0.f;
  }

  // Hoist conv1 weights to SGPRs (block-uniform).
  float wv1[8][9], bb1[8];
#pragma unroll
  for (int oc = 0; oc < 8; ++oc) {
#pragma unroll
    for (int k = 0; k < 9; ++k) wv1[oc][k] = uload(w1 + oc * 9 + k);
    bb1[oc] = uload(b1 + oc);
  }

  // ---- conv1 + ReLU + 2x2 pool -> p1[oc][gl][px+1], gl = 0..17 ----
  // pooled1 global row G = 16q - 1 + gl; x rows 2G-1..2G+2, cols 2px-1..2px+2.
#pragma unroll 1
  for (int pos = tid; pos < 18 * 64; pos += 256) {
    const int gl = pos >> 6, px = pos & 63;
    const int G = 16 * q - 1 + gl;
    const bool validG = (G >= 0) && (G < 64);
    const int xr0 = 2 * G - 1;
    float xin[4][4];
#pragma unroll
    for (int r = 0; r < 4; ++r) {
      const int row = xr0 + r;
      const bool rok = validG && (row >= 0) && (row < 128);
      const float* rp = xb + row * 128;
#pragma unroll
      for (int c = 0; c < 4; ++c) {
        const int col = 2 * px - 1 + c;
        const bool ok = rok && (col >= 0) && (col < 128);
        xin[r][c] = ok ? rp[col] : 0.f;
      }
    }
#pragma unroll
    for (int oc = 0; oc < 8; ++oc) {
      float best = 0.f;  // ReLU floor
#pragma unroll
      for (int dy = 0; dy < 2; ++dy)
#pragma unroll
        for (int dx = 0; dx < 2; ++dx) {
          float a = bb1[oc];
#pragma unroll
          for (int ky = 0; ky < 3; ++ky)
#pragma unroll
            for (int kx = 0; kx < 3; ++kx)
              a = fmaf(xin[dy + ky][dx + kx], wv1[oc][ky * 3 + kx], a);
          best = fmaxf(best, a);
        }
      p1[oc][gl][px + 1] = validG ? best : 0.f;
    }
  }
  __syncthreads();

  // ---- conv2 (oc 0..3) + ReLU + 2x2 pool + accumulate ----
  const int px2  = tid & 31;
  const int py2l = tid >> 5;  // 0..7

  float acc[4][2][2];
#pragma unroll
  for (int oc = 0; oc < 4; ++oc) {
    float bias = uload(b2 + oc);
    acc[oc][0][0] = bias; acc[oc][0][1] = bias;
    acc[oc][1][0] = bias; acc[oc][1][1] = bias;
  }

#pragma unroll 1
  for (int ic = 0; ic < 8; ++ic) {
    float xin[4][4];
#pragma unroll
    for (int r = 0; r < 4; ++r) {
      // 2*px2 is even and row bases are even -> 8B-aligned float2 reads
      // (2-way bank aliasing across 32 lanes — free on CDNA4).
      const f2* rp = (const f2*)&p1[ic][2 * py2l + r][2 * px2];
      f2 v0 = rp[0], v1 = rp[1];
      xin[r][0] = v0.x; xin[r][1] = v0.y; xin[r][2] = v1.x; xin[r][3] = v1.y;
    }
#pragma unroll
    for (int oc = 0; oc < 4; ++oc) {
      float wv[9];
#pragma unroll
      for (int k = 0; k < 9; ++k) wv[k] = uload(w2 + (oc * 8 + ic) * 9 + k);
#pragma unroll
      for (int dy = 0; dy < 2; ++dy)
#pragma unroll
        for (int dx = 0; dx < 2; ++dx) {
#pragma unroll
          for (int ky = 0; ky < 3; ++ky)
#pragma unroll
            for (int kx = 0; kx < 3; ++kx)
              acc[oc][dy][dx] =
                  fmaf(xin[dy + ky][dx + kx], wv[ky * 3 + kx], acc[oc][dy][dx]);
        }
    }
  }

  const int lane = tid & 63, w = tid >> 6;
#pragma unroll
  for (int oc = 0; oc < 4; ++oc) {
    float p = fmaxf(fmaxf(fmaxf(acc[oc][0][0], acc[oc][0][1]),
                          fmaxf(acc[oc][1][0], acc[oc][1][1])), 0.f);
#pragma unroll
    for (int off = 32; off > 0; off >>= 1) p += __shfl_down(p, off);
    if (lane == 0) wred[w][oc] = p;
  }
  __syncthreads();
  if (tid < 4) {
    float s = wred[0][tid] + wred[1][tid] + wred[2][tid] + wred[3][tid];
    partials[((size_t)b * 4 + q) * 4 + tid] = s;
  }
}

// ---------------------------------------------------------------------------
// K3: feats -> quantum circuit -> batchnorm (over batch=512) -> head.
// Single block, 512 threads; thread = batch element. Shuffle reductions.
// ---------------------------------------------------------------------------
__global__ __launch_bounds__(512) void k3_tail(
    const float* __restrict__ partials, const float* __restrict__ qp,
    const float* __restrict__ gamma, const float* __restrict__ beta,
    const float* __restrict__ hw, const float* __restrict__ hb,
    float* __restrict__ out) {
  __shared__ float wsum[8][8];
  __shared__ float stats[8];
  const int tid = threadIdx.x;  // batch index

  // partials[tid][0..15] = 4 strips x 4 oc, contiguous 64B -> 4x dwordx4.
  const f4* pp = (const f4*)(partials + tid * 16);
  f4 s0 = pp[0], s1 = pp[1], s2 = pp[2], s3 = pp[3];
  float f[4];
  f[0] = (s0.x + s1.x + s2.x + s3.x) * (1.f / 1024.f);
  f[1] = (s0.y + s1.y + s2.y + s3.y) * (1.f / 1024.f);
  f[2] = (s0.z + s1.z + s2.z + s3.z) * (1.f / 1024.f);
  f[3] = (s0.w + s1.w + s2.w + s3.w) * (1.f / 1024.f);

  // Per-wire single-qubit amplitudes: a0 = cx*cy - i*sx*sy, a1 = cx*sy - i*sx*cy
  float a0r[4], a0i[4], a1r[4], a1i[4];
#pragma unroll
  for (int i = 0; i < 4; ++i) {
    float cy, sy, cx, sx;
    __sincosf(0.5f * f[i], &sy, &cy);              // args are O(0.1): safe
    __sincosf(0.5f * uload(qp + i), &sx, &cx);
    a0r[i] = cx * cy; a0i[i] = -sx * sy;
    a1r[i] = cx * sy; a1i[i] = -sx * cy;
  }

  // psi[j] = prod over wires of a_{bit}(wire), wire 0 = MSB
  float pr[16], pi[16];
#pragma unroll
  for (int j = 0; j < 16; ++j) {
    float rr = 1.f, ii = 0.f;
#pragma unroll
    for (int w = 0; w < 4; ++w) {
      int bit = (j >> (3 - w)) & 1;
      float ar = bit ? a1r[w] : a0r[w];
      float ai = bit ? a1i[w] : a0i[w];
      float t = rr * ar - ii * ai;
      ii = rr * ai + ii * ar;
      rr = t;
    }
    pr[j] = rr; pi[j] = ii;
  }

  // Composed CNOT(0,1);CNOT(1,2);CNOT(2,3) permutation (new[j] = old[comp[j]])
  constexpr int comp[16] = {0, 1, 3, 2, 6, 7, 5, 4, 12, 13, 15, 14, 10, 11, 9, 8};
  float qv[4] = {0.f, 0.f, 0.f, 0.f};
#pragma unroll
  for (int j = 0; j < 16; ++j) {
    int s = comp[j];
    float p = pr[s] * pr[s] + pi[s] * pi[s];
#pragma unroll
    for (int i = 0; i < 4; ++i)
      qv[i] += ((j >> (3 - i)) & 1) ? -p : p;
  }

  // Batch sums of q and q^2 via wave shuffles, then cross-wave LDS combine.
  float v[8];
#pragma unroll
  for (int i = 0; i < 4; ++i) { v[i] = qv[i]; v[4 + i] = qv[i] * qv[i]; }
#pragma unroll
  for (int k = 0; k < 8; ++k)
#pragma unroll
    for (int off = 32; off > 0; off >>= 1) v[k] += __shfl_down(v[k], off);
  const int lane = tid & 63, w = tid >> 6;
  if (lane == 0) {
#pragma unroll
    for (int k = 0; k < 8; ++k) wsum[w][k] = v[k];
  }
  __syncthreads();
  if (tid < 8) {
    float s = 0.f;
#pragma unroll
    for (int ww = 0; ww < 8; ++ww) s += wsum[ww][tid];
    stats[tid] = s * (1.f / 512.f);
  }
  __syncthreads();

  float nm[4];
#pragma unroll
  for (int i = 0; i < 4; ++i) {
    float mu  = stats[i];
    float var = stats[4 + i] - mu * mu;
    nm[i] = uload(gamma + i) * (qv[i] - mu) * rsqrtf(var + EPS) + uload(beta + i);
  }
#pragma unroll
  for (int k = 0; k < 4; ++k) {
    float o = uload(hb + k);
#pragma unroll
    for (int i = 0; i < 4; ++i) o = fmaf(nm[i], uload(hw + k * 4 + i), o);
    out[tid * 4 + k] = o;
  }
}

extern "C" void kernel_launch(void* const* d_in, const int* in_sizes, int n_in,
                              void* d_out, int out_size, void* d_ws, size_t ws_size,
                              hipStream_t stream) {
  const float* x  = (const float*)d_in[0];
  const float* w1 = (const float*)d_in[1];
  const float* b1 = (const float*)d_in[2];
  const float* w2 = (const float*)d_in[3];
  const float* b2 = (const float*)d_in[4];
  const float* qp = (const float*)d_in[5];
  const float* gm = (const float*)d_in[6];
  const float* bt = (const float*)d_in[7];
  const float* hw = (const float*)d_in[8];
  const float* hb = (const float*)d_in[9];
  float* out = (float*)d_out;

  float* partials = (float*)d_ws;  // 512 * 4 strips * 4 oc floats = 32 KB

  k12_fused<<<512 * 4, 256, 0, stream>>>(x, w1, b1, w2, b2, partials);
  k3_tail<<<1, 512, 0, stream>>>(partials, qp, gm, bt, hw, hb, out);
}